// Round 1
// baseline (781.425 us; speedup 1.0000x reference)
//
#include <hip/hip_runtime.h>
#include <cstdint>
#include <cstddef>

typedef __bf16 bf16;
typedef __bf16 bf16x8 __attribute__((ext_vector_type(8)));
typedef float  f32x4  __attribute__((ext_vector_type(4)));

#define MFMA16(a, b, c) __builtin_amdgcn_mfma_f32_16x16x32_bf16((a), (b), (c), 0, 0, 0)

// async global->LDS, 16B per lane. lptr must be wave-uniform; HW adds lane*16.
__device__ __forceinline__ void async16(const bf16* g, bf16* l) {
  __builtin_amdgcn_global_load_lds(
      (const __attribute__((address_space(1))) unsigned int*)g,
      (__attribute__((address_space(3))) unsigned int*)l, 16, 0, 0);
}

// ---------------- elementwise cast fp32 -> bf16 (4 elems/thread) ----------------
__global__ __launch_bounds__(256) void k_cast(const float* __restrict__ x, bf16* __restrict__ y) {
  size_t i = ((size_t)blockIdx.x * 256 + threadIdx.x) * 4;
  float4 a = *(const float4*)(x + i);
  union { bf16 h[4]; uint2 u; } pk;
  pk.h[0] = (bf16)a.x; pk.h[1] = (bf16)a.y; pk.h[2] = (bf16)a.z; pk.h[3] = (bf16)a.w;
  *(uint2*)(y + i) = pk.u;
}

// ---------------- W[K,N] fp32 -> WT[N,K] bf16, tiled transpose ----------------
__global__ __launch_bounds__(256) void k_transpose_cast(const float* __restrict__ W,
                                                        bf16* __restrict__ WT, int K, int N) {
  __shared__ float tile[32][33];
  int k0 = blockIdx.y << 5, n0 = blockIdx.x << 5;
  int r = threadIdx.x >> 5, c = threadIdx.x & 31;
#pragma unroll
  for (int p = 0; p < 4; p++)
    tile[r + p * 8][c] = W[(size_t)(k0 + r + p * 8) * N + n0 + c];
  __syncthreads();
#pragma unroll
  for (int p = 0; p < 4; p++) {
    int nn = r + p * 8;
    WT[(size_t)(n0 + nn) * K + k0 + c] = (bf16)tile[c][nn];
  }
}

// ---------------- GEMM: C[M,N] = A[M,K] * Bt[N,K]^T  (bf16 in, fp32 acc) ----------------
// m97 structure: 128x128 tile, BK=64, global_load_lds 16B staging, 16x16x32 MFMA.
template <int OUT_BF16>
__global__ __launch_bounds__(256) void k_gemm_bt(const bf16* __restrict__ A,
                                                 const bf16* __restrict__ Bt,
                                                 void* __restrict__ C, int M, int N, int K) {
  __shared__ bf16 a_lds[128 * 64];
  __shared__ bf16 b_lds[128 * 64];
  int tid = threadIdx.x;
  int wave = tid >> 6, lane = tid & 63, quad = lane >> 4, l16 = lane & 15;
  int wr = wave >> 1, wc = wave & 1;
  int m0 = blockIdx.y << 7, n0 = blockIdx.x << 7;
  f32x4 acc[4][4] = {};
  const bf16* ag = A + (size_t)(m0 + (tid >> 3)) * K + (tid & 7) * 8;
  const bf16* bg = Bt + (size_t)(n0 + (tid >> 3)) * K + (tid & 7) * 8;
  bf16* al = a_lds + wave * 512;
  bf16* bl = b_lds + wave * 512;
  for (int kt = 0; kt < K; kt += 64) {
#pragma unroll
    for (int i = 0; i < 4; i++) {
      async16(ag + (size_t)i * 32 * K, al + i * 2048);
      async16(bg + (size_t)i * 32 * K, bl + i * 2048);
    }
    ag += 64; bg += 64;
    __syncthreads();
#pragma unroll
    for (int kk = 0; kk < 2; kk++) {
      bf16x8 af[4], bfv[4];
#pragma unroll
      for (int mt = 0; mt < 4; mt++)
        af[mt] = *(const bf16x8*)&a_lds[(wr * 64 + mt * 16 + l16) * 64 + kk * 32 + quad * 8];
#pragma unroll
      for (int nt = 0; nt < 4; nt++)
        bfv[nt] = *(const bf16x8*)&b_lds[(wc * 64 + nt * 16 + l16) * 64 + kk * 32 + quad * 8];
#pragma unroll
      for (int mt = 0; mt < 4; mt++)
#pragma unroll
        for (int nt = 0; nt < 4; nt++)
          acc[mt][nt] = MFMA16(af[mt], bfv[nt], acc[mt][nt]);
    }
    __syncthreads();
  }
#pragma unroll
  for (int mt = 0; mt < 4; mt++)
#pragma unroll
    for (int nt = 0; nt < 4; nt++)
#pragma unroll
      for (int r = 0; r < 4; r++) {
        int row = m0 + wr * 64 + mt * 16 + quad * 4 + r;
        int col = n0 + wc * 64 + nt * 16 + l16;
        if (OUT_BF16)
          ((bf16*)C)[(size_t)row * N + col] = (bf16)acc[mt][nt][r];
        else
          ((float*)C)[(size_t)row * N + col] = acc[mt][nt][r];
      }
}

// ---------------- rotary (in-place, bf16), row = (b*2048+t)*8+h, 256 elems ----------------
__global__ __launch_bounds__(256) void k_rotary(bf16* __restrict__ x, float scale) {
  int tid = threadIdx.x;
  int row = blockIdx.x * 2 + (tid >> 7);
  int j = tid & 127;
  int t = (row >> 3) & 2047;
  // inv = 10000^(-2j/256) = exp2(-j * (2/256)*log2(10000))
  float inv = exp2f(-0.10381025296522976f * (float)j);
  float ang = (float)t * inv;
  float s, c;
  sincosf(ang, &s, &c);
  size_t base = (size_t)row * 256;
  float x1 = (float)x[base + j], x2 = (float)x[base + j + 128];
  x[base + j]       = (bf16)((x1 * c - x2 * s) * scale);
  x[base + j + 128] = (bf16)((x2 * c + x1 * s) * scale);
}

// ---------------- retention scan ----------------
// grid = 256 WGs: gid -> kh(1b) | vb(3b) | h(3b) | b(1b). Each WG owns the
// (b,h) scan for v-cols [vb*64, +64) and k-rows [kh*128, +128). All decays are
// per-row linear scalings, so the two kh partials sum exactly (o0 + o1).
__global__ __launch_bounds__(256) void k_retention(const bf16* __restrict__ q,
                                                   const bf16* __restrict__ k,
                                                   const bf16* __restrict__ v,
                                                   float* __restrict__ o0,
                                                   float* __restrict__ o1) {
  __shared__ bf16 q_lds[64][136];   // [c][k]  (+8 pad: 272B stride, 16B aligned)
  __shared__ bf16 k_lds[64][136];   // [c][k]
  __shared__ bf16 St_lds[64][136];  // [v][k]  S^T, bf16 copy of state
  __shared__ bf16 kt_lds[128][88];  // [k][c]  (+24 pad: 176B stride, conflict-free)
  __shared__ bf16 vt_lds[64][88];   // [v][c]
  __shared__ bf16 v2t_lds[64][88];  // [v][c]  v scaled by kd[c]
  __shared__ bf16 A_lds[64][88];    // [c][c'] masked score

  int gid = blockIdx.x;
  int kh = gid & 1, vb = (gid >> 1) & 7, h = (gid >> 4) & 7, b = gid >> 7;
  float* oout = kh ? o1 : o0;
  int tid = threadIdx.x, lane = tid & 63, wave = tid >> 6, quad = lane >> 4, l16 = lane & 15;
  int wr = wave >> 1, wc = wave & 1;
  float gamma = 1.f - exp2f(-5.f - (float)h);
  float lg = log2f(gamma);
  float gC = exp2f(64.f * lg);

  f32x4 S[8];  // wave's state strip: k in [wave*32, +32), tiles a(2) x bb(4)
#pragma unroll
  for (int i = 0; i < 8; i++) S[i] = (f32x4){0.f, 0.f, 0.f, 0.f};

  for (int n = 0; n < 32; n++) {
    int t0 = n * 64;
    __syncthreads();
    // (1) St_lds[v][k] <- bf16(S)   (C-layout regs -> transposed LDS, b64 stores)
#pragma unroll
    for (int a = 0; a < 2; a++)
#pragma unroll
      for (int bb = 0; bb < 4; bb++) {
        int k0 = wave * 32 + a * 16 + quad * 4;
        int vc = bb * 16 + l16;
        f32x4 s = S[a * 4 + bb];
        union { bf16 hh[4]; unsigned long long u; } pk;
        pk.hh[0] = (bf16)s[0]; pk.hh[1] = (bf16)s[1];
        pk.hh[2] = (bf16)s[2]; pk.hh[3] = (bf16)s[3];
        *(unsigned long long*)&St_lds[vc][k0] = pk.u;
      }
    // (2) stage q
#pragma unroll
    for (int p = 0; p < 4; p++) {
      int c = p * 16 + (tid >> 4);
      int ko = (tid & 15) * 8;
      const bf16* src = q + (((size_t)(b * 2048 + t0 + c) * 8 + h) << 8) + kh * 128 + ko;
      *(uint4*)&q_lds[c][ko] = *(const uint4*)src;
    }
    // stage k + kt
#pragma unroll
    for (int p = 0; p < 4; p++) {
      int c = p * 16 + (tid >> 4);
      int ko = (tid & 15) * 8;
      const bf16* src = k + (((size_t)(b * 2048 + t0 + c) * 8 + h) << 8) + kh * 128 + ko;
      uint4 d = *(const uint4*)src;
      *(uint4*)&k_lds[c][ko] = d;
      const bf16* e = (const bf16*)&d;
#pragma unroll
      for (int j = 0; j < 8; j++) kt_lds[ko + j][c] = e[j];
    }
    // stage v -> vt, v2t (v2 = kd[c]*v; folds kd into the kv product)
#pragma unroll
    for (int p = 0; p < 2; p++) {
      int c = p * 32 + (tid >> 3);
      int jo = (tid & 7) * 8;
      const bf16* src = v + ((size_t)(b * 2048 + t0 + c)) * 4096 + h * 512 + vb * 64 + jo;
      uint4 d = *(const uint4*)src;
      const bf16* e = (const bf16*)&d;
      float kd = exp2f(lg * (float)(63 - c));
#pragma unroll
      for (int j = 0; j < 8; j++) {
        vt_lds[jo + j][c] = e[j];
        v2t_lds[jo + j][c] = (bf16)(kd * (float)e[j]);
      }
    }
    __syncthreads();
    // (3) A = (q k^T) ∘ D  -> A_lds   (partial over this k-half; mask is linear)
#pragma unroll
    for (int it = 0; it < 2; it++) {
      int ar = wr * 32 + it * 16 + l16;
      bf16x8 af[4];
#pragma unroll
      for (int kk = 0; kk < 4; kk++) af[kk] = *(const bf16x8*)&q_lds[ar][kk * 32 + quad * 8];
#pragma unroll
      for (int jt = 0; jt < 2; jt++) {
        int br = wc * 32 + jt * 16 + l16;
        f32x4 aacc = (f32x4){0.f, 0.f, 0.f, 0.f};
#pragma unroll
        for (int kk = 0; kk < 4; kk++) {
          bf16x8 bfv = *(const bf16x8*)&k_lds[br][kk * 32 + quad * 8];
          aacc = MFMA16(af[kk], bfv, aacc);
        }
        int i0 = wr * 32 + it * 16 + quad * 4;
        int j = wc * 32 + jt * 16 + l16;
#pragma unroll
        for (int r = 0; r < 4; r++) {
          int d = i0 + r - j;
          float val = (d >= 0) ? aacc[r] * exp2f(lg * (float)d) : 0.f;
          A_lds[i0 + r][j] = (bf16)val;
        }
      }
    }
    __syncthreads();
    // (4) o = diag(qd)*(q @ S) + (A @ v)
    f32x4 oacc[2][2];
    oacc[0][0] = (f32x4){0.f, 0.f, 0.f, 0.f}; oacc[0][1] = (f32x4){0.f, 0.f, 0.f, 0.f};
    oacc[1][0] = (f32x4){0.f, 0.f, 0.f, 0.f}; oacc[1][1] = (f32x4){0.f, 0.f, 0.f, 0.f};
#pragma unroll
    for (int mt = 0; mt < 2; mt++) {
      int ar = wr * 32 + mt * 16 + l16;
      bf16x8 af[4];
#pragma unroll
      for (int kk = 0; kk < 4; kk++) af[kk] = *(const bf16x8*)&q_lds[ar][kk * 32 + quad * 8];
#pragma unroll
      for (int nt = 0; nt < 2; nt++) {
        int br = wc * 32 + nt * 16 + l16;
#pragma unroll
        for (int kk = 0; kk < 4; kk++) {
          bf16x8 bfv = *(const bf16x8*)&St_lds[br][kk * 32 + quad * 8];
          oacc[mt][nt] = MFMA16(af[kk], bfv, oacc[mt][nt]);
        }
      }
    }
#pragma unroll
    for (int mt = 0; mt < 2; mt++) {
      int i0 = wr * 32 + mt * 16 + quad * 4;
#pragma unroll
      for (int r = 0; r < 4; r++) {
        float qd = exp2f(lg * (float)(i0 + r + 1));
        oacc[mt][0][r] *= qd;
        oacc[mt][1][r] *= qd;
      }
    }
    {
      bf16x8 bfr[2][2];
#pragma unroll
      for (int nt = 0; nt < 2; nt++)
#pragma unroll
        for (int kk = 0; kk < 2; kk++)
          bfr[nt][kk] = *(const bf16x8*)&vt_lds[wc * 32 + nt * 16 + l16][kk * 32 + quad * 8];
#pragma unroll
      for (int mt = 0; mt < 2; mt++) {
        bf16x8 af2[2];
#pragma unroll
        for (int kk = 0; kk < 2; kk++)
          af2[kk] = *(const bf16x8*)&A_lds[wr * 32 + mt * 16 + l16][kk * 32 + quad * 8];
#pragma unroll
        for (int nt = 0; nt < 2; nt++)
#pragma unroll
          for (int kk = 0; kk < 2; kk++)
            oacc[mt][nt] = MFMA16(af2[kk], bfr[nt][kk], oacc[mt][nt]);
      }
    }
#pragma unroll
    for (int mt = 0; mt < 2; mt++)
#pragma unroll
      for (int nt = 0; nt < 2; nt++)
#pragma unroll
        for (int r = 0; r < 4; r++) {
          int rowt = t0 + wr * 32 + mt * 16 + quad * 4 + r;
          int col = vb * 64 + wc * 32 + nt * 16 + l16;
          oout[(((size_t)(b * 2048 + rowt)) * 8 + h) * 512 + col] = oacc[mt][nt][r];
        }
    // (5) S = gC*S + k^T @ v2   (MFMA accumulates on the fp32 master state)
    {
      bf16x8 bfr[4][2];
#pragma unroll
      for (int bb = 0; bb < 4; bb++)
#pragma unroll
        for (int kk = 0; kk < 2; kk++)
          bfr[bb][kk] = *(const bf16x8*)&v2t_lds[bb * 16 + l16][kk * 32 + quad * 8];
#pragma unroll
      for (int a = 0; a < 2; a++) {
        bf16x8 af3[2];
#pragma unroll
        for (int kk = 0; kk < 2; kk++)
          af3[kk] = *(const bf16x8*)&kt_lds[wave * 32 + a * 16 + l16][kk * 32 + quad * 8];
#pragma unroll
        for (int bb = 0; bb < 4; bb++) {
          f32x4 cc = S[a * 4 + bb] * gC;
#pragma unroll
          for (int kk = 0; kk < 2; kk++) cc = MFMA16(af3[kk], bfr[bb][kk], cc);
          S[a * 4 + bb] = cc;
        }
      }
    }
  }
}

// ---------------- fused RMSNorm (per 512) + swish gate, -> bf16 ----------------
__global__ __launch_bounds__(256) void k_normgate(const float* __restrict__ o0,
                                                  const float* __restrict__ o1,
                                                  const bf16* __restrict__ g,
                                                  const float* __restrict__ gw,
                                                  bf16* __restrict__ og) {
  int tid = threadIdx.x, lane = tid & 63;
  size_t row = (size_t)blockIdx.x * 4 + (tid >> 6);
  size_t base = row * 512;
  float vv[8];
  float ss = 0.f;
#pragma unroll
  for (int hh = 0; hh < 2; hh++) {
    int col = hh * 256 + lane * 4;
    float4 a = *(const float4*)(o0 + base + col);
    float4 b = *(const float4*)(o1 + base + col);
    vv[hh * 4 + 0] = a.x + b.x; vv[hh * 4 + 1] = a.y + b.y;
    vv[hh * 4 + 2] = a.z + b.z; vv[hh * 4 + 3] = a.w + b.w;
#pragma unroll
    for (int jj = 0; jj < 4; jj++) ss += vv[hh * 4 + jj] * vv[hh * 4 + jj];
  }
#pragma unroll
  for (int off = 1; off < 64; off <<= 1) ss += __shfl_xor(ss, off, 64);
  float rinv = rsqrtf(ss * (1.0f / 512.0f) + 1e-5f);
#pragma unroll
  for (int hh = 0; hh < 2; hh++) {
    int col = hh * 256 + lane * 4;
    union { bf16 h[4]; uint2 u; } gp;
    gp.u = *(const uint2*)(g + base + col);
    union { bf16 h[4]; uint2 u; } op;
#pragma unroll
    for (int jj = 0; jj < 4; jj++) {
      float gg = (float)gp.h[jj];
      float y = vv[hh * 4 + jj] * rinv * gw[col + jj] * (gg / (1.f + expf(-gg)));
      op.h[jj] = (bf16)y;
    }
    *(uint2*)(og + base + col) = op.u;
  }
}

extern "C" void kernel_launch(void* const* d_in, const int* in_sizes, int n_in,
                              void* d_out, int out_size, void* d_ws, size_t ws_size,
                              hipStream_t stream) {
  (void)in_sizes; (void)n_in; (void)out_size; (void)ws_size;
  const float* hs = (const float*)d_in[0];
  const float* Wq = (const float*)d_in[1];
  const float* Wk = (const float*)d_in[2];
  const float* Wv = (const float*)d_in[3];
  const float* Wg = (const float*)d_in[4];
  const float* Wo = (const float*)d_in[5];
  const float* gw = (const float*)d_in[6];
  float* out = (float*)d_out;

  char* ws = (char*)d_ws;
  const size_t MB = 1024 * 1024;
  // live-range overlays (stream-serialized): peak 224 MB
  bf16* hid = (bf16*)(ws + 0);          // [0,16)   dead after g GEMM
  bf16* WqT = (bf16*)(ws + 16 * MB);    // [16,24)  dead after q GEMM
  bf16* WkT = (bf16*)(ws + 24 * MB);    // [24,32)
  bf16* WvT = (bf16*)(ws + 32 * MB);    // [32,48)
  bf16* WgT = (bf16*)(ws + 48 * MB);    // [48,64)
  bf16* qb  = (bf16*)(ws + 64 * MB);    // [64,80)  dead after retention
  bf16* kb  = (bf16*)(ws + 80 * MB);    // [80,96)
  bf16* vbuf= (bf16*)(ws + 96 * MB);    // [96,128) dead after retention
  bf16* gb  = (bf16*)(ws + 128 * MB);   // [128,160) dead after normgate
  float* o0 = (float*)(ws + 0);         // [0,64)   overlays hid+W casts
  bf16* og  = (bf16*)(ws + 64 * MB);    // [64,96)  overlays qb,kb
  bf16* WoT = (bf16*)(ws + 96 * MB);    // [96,112) overlays vbuf (cast after retention)
  float* o1 = (float*)(ws + 160 * MB);  // [160,224)

  k_cast<<<8192, 256, 0, stream>>>(hs, hid);
  k_transpose_cast<<<dim3(64, 64), 256, 0, stream>>>(Wq, WqT, 2048, 2048);
  k_transpose_cast<<<dim3(64, 64), 256, 0, stream>>>(Wk, WkT, 2048, 2048);
  k_transpose_cast<<<dim3(128, 64), 256, 0, stream>>>(Wv, WvT, 2048, 4096);
  k_transpose_cast<<<dim3(128, 64), 256, 0, stream>>>(Wg, WgT, 2048, 4096);

  k_gemm_bt<1><<<dim3(16, 32), 256, 0, stream>>>(hid, WqT, qb, 4096, 2048, 2048);
  k_gemm_bt<1><<<dim3(16, 32), 256, 0, stream>>>(hid, WkT, kb, 4096, 2048, 2048);
  k_gemm_bt<1><<<dim3(32, 32), 256, 0, stream>>>(hid, WvT, vbuf, 4096, 4096, 2048);
  k_gemm_bt<1><<<dim3(32, 32), 256, 0, stream>>>(hid, WgT, gb, 4096, 4096, 2048);

  k_rotary<<<16384, 256, 0, stream>>>(qb, 0.0625f);  // fold DK^-0.5 into q
  k_rotary<<<16384, 256, 0, stream>>>(kb, 1.0f);

  k_retention<<<256, 256, 0, stream>>>(qb, kb, vbuf, o0, o1);

  k_transpose_cast<<<dim3(64, 128), 256, 0, stream>>>(Wo, WoT, 4096, 2048);
  k_normgate<<<8192, 256, 0, stream>>>(o0, o1, gb, gw, og);
  k_gemm_bt<0><<<dim3(16, 32), 256, 0, stream>>>(og, WoT, out, 4096, 2048, 4096);
}